// Round 11
// baseline (225.401 us; speedup 1.0000x reference)
//
#include <hip/hip_runtime.h>
#include <hip/hip_bf16.h>

typedef unsigned short ushort_t;
typedef unsigned int uint_t;
typedef __attribute__((ext_vector_type(8))) short v8s;   // 8 x bf16 (4 VGPRs)
typedef __attribute__((ext_vector_type(4))) float v4f;   // MFMA accumulator / float4

#define BN_SCALE 0.9999950000374997f

__device__ __forceinline__ float bf2f(ushort_t u) {
    union { uint_t i; float f; } v;
    v.i = ((uint_t)u) << 16;
    return v.f;
}
__device__ __forceinline__ ushort_t f2bf(float f) {
    union { uint_t i; float f; } v;
    v.f = f;
    uint_t b = v.i;
    b += 0x7fffu + ((b >> 16) & 1u);   // RNE
    return (ushort_t)(b >> 16);
}

__device__ __forceinline__ v8s cvt8(const float* __restrict__ p) {
    v8s f;
    #pragma unroll
    for (int j = 0; j < 8; ++j) f[j] = (short)f2bf(p[j]);
    return f;
}

// ---------------------------------------------------------------------------
// Kernel 0: convert f32 -> bf16 (used for out_w, m0_w, m1_w), 1024 elem/block.
// ---------------------------------------------------------------------------
__global__ __launch_bounds__(256) void convw_kernel(
    const float* __restrict__ w, ushort_t* __restrict__ wb)
{
    const int i = (blockIdx.x * 256 + threadIdx.x) * 4;
    const v4f v = *(const v4f*)(w + i);
    ushort_t r0 = f2bf(v[0]), r1 = f2bf(v[1]), r2 = f2bf(v[2]), r3 = f2bf(v[3]);
    uint_t lo = (uint_t)r0 | ((uint_t)r1 << 16);
    uint_t hi = (uint_t)r2 | ((uint_t)r3 << 16);
    *(uint2*)(wb + i) = make_uint2(lo, hi);
}

// ---------------------------------------------------------------------------
// Kernel 1: cur{0,1}[n][d] = src_feats[n] . fc{0,1}_w[d] + fc{0,1}_b[d]
// Pure-MFMA GEMM, no LDS, bias folded into acc init. 64 rows/block.
// ---------------------------------------------------------------------------
__global__ __launch_bounds__(256) void cur_kernel(
    const float* __restrict__ src_feats,                     // (N,64) f32
    const float* __restrict__ fc0_w, const float* __restrict__ fc0_b,
    const float* __restrict__ fc1_w, const float* __restrict__ fc1_b,
    ushort_t* __restrict__ cur0, ushort_t* __restrict__ cur1)
{
    const int tid  = threadIdx.x;
    const int lane = tid & 63;
    const int wid  = tid >> 6;
    const int col  = lane & 15;
    const int quad = lane >> 4;
    const int row0 = blockIdx.x * 64 + wid * 16;

    v8s afrag[2];
    #pragma unroll
    for (int kf = 0; kf < 2; ++kf)
        afrag[kf] = cvt8(src_feats + (size_t)(row0 + col) * 64 + kf * 32 + quad * 8);

    v4f acc[8];
    v8s bfrag[8][2];
    #pragma unroll
    for (int ct = 0; ct < 8; ++ct) {
        const int d = (ct & 3) * 16 + col;
        const float* w = (ct < 4 ? fc0_w : fc1_w) + d * 64;
        const float  b = (ct < 4 ? fc0_b : fc1_b)[d];
        acc[ct] = (v4f){b, b, b, b};
        #pragma unroll
        for (int kf = 0; kf < 2; ++kf)
            bfrag[ct][kf] = cvt8(w + kf * 32 + quad * 8);
    }

    #pragma unroll
    for (int kf = 0; kf < 2; ++kf)
        #pragma unroll
        for (int ct = 0; ct < 8; ++ct)
            acc[ct] = __builtin_amdgcn_mfma_f32_16x16x32_bf16(
                afrag[kf], bfrag[ct][kf], acc[ct], 0, 0, 0);

    #pragma unroll
    for (int ct = 0; ct < 8; ++ct) {
        ushort_t* dst = (ct < 4) ? cur0 : cur1;
        const int d = (ct & 3) * 16 + col;
        #pragma unroll
        for (int r = 0; r < 4; ++r) {
            const int n = row0 + quad * 4 + r;
            dst[(size_t)n * 64 + d] = f2bf(acc[ct][r]);
        }
    }
}

// ---------------------------------------------------------------------------
// SA layer body. 128 pairs/block (MB=128/S m's), 256 threads (4 waves).
// Prologue: cur rows -> xlds (coalesced b128); (sp-dp) -> flds.
// Phase A (paired-d): lane handles pair=lane>>5, d=(lane&31)*2 +{0,1}.
// Phase B (wave-owns-mi): wave wid computes mi=wid(+4) over ALL 8 col-tiles
//   with 2 live accumulators (epilogue-reduce per ct). afrag read ONCE per
//   wave for its own mi -> phase-B LDS reads / 4. bfrag from pre-converted
//   bf16 m_wb (no in-kernel f32->bf16).
// ---------------------------------------------------------------------------
template <int S>
__device__ __forceinline__ void sa_body(
    const int bid,
    const float* __restrict__ src_xyz,   // (N,3) f32
    const float* __restrict__ dst_xyz,   // (M,3) f32
    const int*   __restrict__ idx,       // (M,S)
    const int*   __restrict__ empty,     // (M,)
    const float* __restrict__ p_w,       // (64,6)
    const float* __restrict__ p_g,
    const float* __restrict__ p_b,
    const ushort_t* __restrict__ m_wb,   // (128,64) bf16 (pre-converted)
    const float* __restrict__ m_g,
    const float* __restrict__ m_b,
    const ushort_t* __restrict__ cur,    // (N,64) bf16
    ushort_t*    __restrict__ f01,       // (M,256) bf16
    const int layer_off,
    ushort_t* xlds,                      // [128 * 72]
    v4f*      flds)                      // [128]
{
    constexpr int PAIRS = 128;
    constexpr int MB = PAIRS / S;        // 4 (S=32) or 8 (S=16)
    constexpr int XP = 72;               // padded row stride (ushorts), 144 B
    constexpr int T  = S / 4;            // pairs per (wave, mi) in phase A
    constexpr int RT = S / 16;           // 16-row tiles per mi
    constexpr int MW = MB / 4;           // mi's per wave in phase B

    const int tid  = threadIdx.x;
    const int lane = tid & 63;
    const int wid  = tid >> 6;           // 0..3
    const int m0   = bid * MB;

    // ---- prologue 1: cur rows -> xlds (coalesced, in-place with x) ----
    {
        const int p  = tid >> 1;         // pair 0..127
        const int hf = tid & 1;
        const int m  = m0 + p / S;
        const int i  = idx[(size_t)m * S + (p & (S - 1))];
        const uint_t* crow = (const uint_t*)(cur + (size_t)i * 64) + hf * 16;
        const uint4 c0 = *(const uint4*)(crow + 0);
        const uint4 c1 = *(const uint4*)(crow + 4);
        const uint4 c2 = *(const uint4*)(crow + 8);
        const uint4 c3 = *(const uint4*)(crow + 12);
        uint_t* drow = (uint_t*)(xlds + p * XP) + hf * 16;
        *(uint4*)(drow + 0)  = c0;
        *(uint4*)(drow + 4)  = c1;
        *(uint4*)(drow + 8)  = c2;
        *(uint4*)(drow + 12) = c3;
    }
    // ---- prologue 2: relative coords -> flds ----
    if (tid < PAIRS) {
        const int p = tid;
        const int m = m0 + p / S;
        const int i = idx[(size_t)m * S + (p & (S - 1))];
        const float dx = dst_xyz[m * 3 + 0];
        const float dy = dst_xyz[m * 3 + 1];
        const float dz = dst_xyz[m * 3 + 2];
        v4f r;
        r[0] = src_xyz[i * 3 + 0] - dx;
        r[1] = src_xyz[i * 3 + 1] - dy;
        r[2] = src_xyz[i * 3 + 2] - dz;
        r[3] = 0.0f;
        flds[p] = r;
    }

    // ---- per-lane paired-d constants (d = dd, dd+1) ----
    const int dd = (lane & 31) * 2;
    const int psub = lane >> 5;          // 0/1: which pair of the iter
    const float pgA = p_g[dd] * BN_SCALE;
    const float pgB = p_g[dd + 1] * BN_SCALE;
    const float pbA = p_b[dd];
    const float pbB = p_b[dd + 1];
    const float pwA0 = p_w[dd * 6 + 0] * pgA;
    const float pwA1 = p_w[dd * 6 + 1] * pgA;
    const float pwA2 = p_w[dd * 6 + 2] * pgA;
    const float pdA0 = p_w[dd * 6 + 3] * pgA;
    const float pdA1 = p_w[dd * 6 + 4] * pgA;
    const float pdA2 = p_w[dd * 6 + 5] * pgA;
    const float pwB0 = p_w[dd * 6 + 6] * pgB;
    const float pwB1 = p_w[dd * 6 + 7] * pgB;
    const float pwB2 = p_w[dd * 6 + 8] * pgB;
    const float pdB0 = p_w[dd * 6 + 9] * pgB;
    const float pdB1 = p_w[dd * 6 + 10] * pgB;
    const float pdB2 = p_w[dd * 6 + 11] * pgB;

    __syncthreads();

    // ================= phase A: paired-d, pure LDS + VALU =================
    const int tbase = wid * T;
    #pragma unroll
    for (int mi = 0; mi < MB; ++mi) {
        const int m = m0 + mi;                        // uniform
        const float dx = dst_xyz[m * 3 + 0];          // s_load
        const float dy = dst_xyz[m * 3 + 1];
        const float dz = dst_xyz[m * 3 + 2];
        const int   em = empty[m];
        const float vbA = fmaf(pdA0, dx, fmaf(pdA1, dy, fmaf(pdA2, dz, pbA)));
        const float vbB = fmaf(pdB0, dx, fmaf(pdB1, dy, fmaf(pdB2, dz, pbB)));

        #pragma unroll
        for (int it = 0; it < T / 2; ++it) {
            const int p = mi * S + tbase + it * 2 + psub;
            const v4f r = flds[p];                    // 2-addr broadcast b128
            const uint_t cu = *(const uint_t*)(xlds + p * XP + dd);   // b32
            const float c0 = __uint_as_float(cu << 16);
            const float c1 = __uint_as_float(cu & 0xffff0000u);

            const float v0 = fmaf(pwA0, r[0], fmaf(pwA1, r[1], fmaf(pwA2, r[2], vbA)));
            const float v1 = fmaf(pwB0, r[0], fmaf(pwB1, r[1], fmaf(pwB2, r[2], vbB)));
            const float rc0 = __builtin_amdgcn_rcpf(1.0f + __expf(-v0));
            const float rc1 = __builtin_amdgcn_rcpf(1.0f + __expf(-v1));
            float x0 = fmaf(v0, rc0, c0);
            float x1 = fmaf(v1, rc1, c1);
            x0 = em ? 0.0f : x0;
            x1 = em ? 0.0f : x1;

            float2 f2; f2.x = x0; f2.y = x1;
            union { __hip_bfloat162 h2; uint_t u; } pk;
            pk.h2 = __float22bfloat162_rn(f2);        // v_cvt_pk_bf16_f32
            *(uint_t*)(xlds + p * XP + dd) = pk.u;    // b32 write in place
        }
    }

    // ---- phase-B per-wave constants: bn params for all 8 col-tiles ----
    const int col  = lane & 15;
    const int quad = lane >> 4;
    float mgv[8], mbv[8];
    #pragma unroll
    for (int ct = 0; ct < 8; ++ct) {
        const int h = ct * 16 + col;
        mgv[ct] = m_g[h] * BN_SCALE;
        mbv[ct] = m_b[h];
    }

    __syncthreads();

    // ================= phase B: wave owns mi, sweeps all col-tiles =========
    #pragma unroll
    for (int mw = 0; mw < MW; ++mw) {
        const int mi = wid + mw * 4;
        const int m  = m0 + mi;

        v8s afrag[RT][2];
        #pragma unroll
        for (int rt = 0; rt < RT; ++rt)
            #pragma unroll
            for (int kf = 0; kf < 2; ++kf)
                afrag[rt][kf] = *(const v8s*)(
                    xlds + (mi * S + rt * 16 + col) * XP + kf * 32 + quad * 8);

        #pragma unroll
        for (int ct = 0; ct < 8; ++ct) {
            const int h = ct * 16 + col;
            v4f acc[RT];
            #pragma unroll
            for (int rt = 0; rt < RT; ++rt) acc[rt] = (v4f)0.0f;

            #pragma unroll
            for (int kf = 0; kf < 2; ++kf) {
                const v8s bfrag = *(const v8s*)(m_wb + h * 64 + kf * 32 + quad * 8);
                #pragma unroll
                for (int rt = 0; rt < RT; ++rt)
                    acc[rt] = __builtin_amdgcn_mfma_f32_16x16x32_bf16(
                        afrag[rt][kf], bfrag, acc[rt], 0, 0, 0);
            }

            // bn, relu, max over s (C/D layout: col=lane&15, row=quad*4+r)
            float vm = 0.0f;   // relu(y)>=0: 0 is a valid identity
            #pragma unroll
            for (int rt = 0; rt < RT; ++rt)
                #pragma unroll
                for (int r = 0; r < 4; ++r) {
                    const float y = fmaf(acc[rt][r], mgv[ct], mbv[ct]);
                    vm = fmaxf(vm, y);
                }
            vm = fmaxf(vm, __shfl_xor(vm, 16));
            vm = fmaxf(vm, __shfl_xor(vm, 32));
            if (lane < 16)
                f01[m * 256 + layer_off + ct * 16 + lane] = f2bf(vm);
        }
    }
}

// ---------------------------------------------------------------------------
// Kernel 2: fused SA layers. Blocks [0, G32) run layer 1 (S=32), blocks
// [G32, G32+G16) run layer 0 (S=16).
// ---------------------------------------------------------------------------
__global__ __launch_bounds__(256, 5) void sa_fused_kernel(
    const float* __restrict__ src_xyz, const float* __restrict__ dst_xyz,
    const int* __restrict__ idx0, const int* __restrict__ empty0,
    const float* __restrict__ p0_w, const float* __restrict__ p0_g, const float* __restrict__ p0_b,
    const ushort_t* __restrict__ m0_wb, const float* __restrict__ m0_g, const float* __restrict__ m0_b,
    const ushort_t* __restrict__ cur0,
    const int* __restrict__ idx1, const int* __restrict__ empty1,
    const float* __restrict__ p1_w, const float* __restrict__ p1_g, const float* __restrict__ p1_b,
    const ushort_t* __restrict__ m1_wb, const float* __restrict__ m1_g, const float* __restrict__ m1_b,
    const ushort_t* __restrict__ cur1,
    ushort_t* __restrict__ f01, const int G32)
{
    __shared__ ushort_t xlds[128 * 72];  // 18432 B
    __shared__ v4f      flds[128];       //  2048 B

    const int b = blockIdx.x;
    if (b < G32)
        sa_body<32>(b, src_xyz, dst_xyz, idx1, empty1, p1_w, p1_g, p1_b,
                    m1_wb, m1_g, m1_b, cur1, f01, 128, xlds, flds);
    else
        sa_body<16>(b - G32, src_xyz, dst_xyz, idx0, empty0, p0_w, p0_g, p0_b,
                    m0_wb, m0_g, m0_b, cur0, f01, 0, xlds, flds);
}

// ---------------------------------------------------------------------------
// Kernel 4: out[m][o] = relu(bn(f01[m] . out_w[o])) via MFMA.
// 16 rows/block, 4 waves split the 256 output cols, K=256.
// ---------------------------------------------------------------------------
__global__ __launch_bounds__(256) void out_kernel(
    const ushort_t* __restrict__ f01,     // (M,256) bf16
    const ushort_t* __restrict__ out_wb,  // (256,256) bf16
    const float*    __restrict__ out_g,
    const float*    __restrict__ out_b,
    float*          __restrict__ out)     // (M,256) f32
{
    const int tid  = threadIdx.x;
    const int lane = tid & 63;
    const int wid  = tid >> 6;
    const int col  = lane & 15;
    const int quad = lane >> 4;
    const int m0   = blockIdx.x * 16;

    v8s afrag[8];
    #pragma unroll
    for (int kf = 0; kf < 8; ++kf)
        afrag[kf] = *(const v8s*)(f01 + (size_t)(m0 + col) * 256 + kf * 32 + quad * 8);

    v4f acc[4];
    #pragma unroll
    for (int c = 0; c < 4; ++c) acc[c] = (v4f)0.0f;

    #pragma unroll
    for (int kf = 0; kf < 8; ++kf) {
        #pragma unroll
        for (int c = 0; c < 4; ++c) {
            const int n = (wid * 4 + c) * 16 + col;
            const v8s b = *(const v8s*)(out_wb + (size_t)n * 256 + kf * 32 + quad * 8);
            acc[c] = __builtin_amdgcn_mfma_f32_16x16x32_bf16(afrag[kf], b, acc[c], 0, 0, 0);
        }
    }

    #pragma unroll
    for (int c = 0; c < 4; ++c) {
        const int n  = (wid * 4 + c) * 16 + col;
        const float og = out_g[n] * BN_SCALE;
        const float ob = out_b[n];
        #pragma unroll
        for (int r = 0; r < 4; ++r) {
            float y = fmaf(acc[c][r], og, ob);
            y = fmaxf(y, 0.0f);
            out[(size_t)(m0 + quad * 4 + r) * 256 + n] = y;
        }
    }
}

// ---------------------------------------------------------------------------
extern "C" void kernel_launch(void* const* d_in, const int* in_sizes, int n_in,
                              void* d_out, int out_size, void* d_ws, size_t ws_size,
                              hipStream_t stream)
{
    const float* src_xyz   = (const float*)d_in[0];
    const float* src_feats = (const float*)d_in[1];
    const float* dst_xyz   = (const float*)d_in[2];
    const int*   idx0      = (const int*)d_in[3];
    const int*   idx1      = (const int*)d_in[4];
    const int*   empty0    = (const int*)d_in[5];
    const int*   empty1    = (const int*)d_in[6];
    const float* fc0_w     = (const float*)d_in[7];
    const float* fc0_b     = (const float*)d_in[8];
    const float* p0_w      = (const float*)d_in[9];
    const float* p0_g      = (const float*)d_in[10];
    const float* p0_b      = (const float*)d_in[11];
    const float* m0_w      = (const float*)d_in[12];
    const float* m0_g      = (const float*)d_in[13];
    const float* m0_b      = (const float*)d_in[14];
    const float* fc1_w     = (const float*)d_in[15];
    const float* fc1_b     = (const float*)d_in[16];
    const float* p1_w      = (const float*)d_in[17];
    const float* p1_g      = (const float*)d_in[18];
    const float* p1_b      = (const float*)d_in[19];
    const float* m1_w      = (const float*)d_in[20];
    const float* m1_g      = (const float*)d_in[21];
    const float* m1_b      = (const float*)d_in[22];
    const float* out_w     = (const float*)d_in[23];
    const float* out_g     = (const float*)d_in[24];
    const float* out_b     = (const float*)d_in[25];

    const int N = in_sizes[0] / 3;   // 65536
    const int M = in_sizes[2] / 3;   // 16384

    // ws layout: cur0 | cur1 (N*64 bf16) | f01 (M*256 bf16) | out_wb | m0_wb | m1_wb
    ushort_t* cur0   = (ushort_t*)d_ws;
    ushort_t* cur1   = cur0 + (size_t)N * 64;
    ushort_t* f01    = cur1 + (size_t)N * 64;
    ushort_t* out_wb = f01 + (size_t)M * 256;
    ushort_t* m0_wb  = out_wb + 256 * 256;
    ushort_t* m1_wb  = m0_wb + 128 * 64;

    const int G32 = M / 4;   // sa32: MB=4
    const int G16 = M / 8;   // sa16: MB=8

    convw_kernel<<<64, 256, 0, stream>>>(out_w, out_wb);
    convw_kernel<<<8, 256, 0, stream>>>(m0_w, m0_wb);
    convw_kernel<<<8, 256, 0, stream>>>(m1_w, m1_wb);
    cur_kernel<<<N / 64, 256, 0, stream>>>(src_feats, fc0_w, fc0_b, fc1_w, fc1_b,
                                           cur0, cur1);
    sa_fused_kernel<<<G32 + G16, 256, 0, stream>>>(
        src_xyz, dst_xyz,
        idx0, empty0, p0_w, p0_g, p0_b, m0_wb, m0_g, m0_b, cur0,
        idx1, empty1, p1_w, p1_g, p1_b, m1_wb, m1_g, m1_b, cur1,
        f01, G32);
    out_kernel<<<M / 16, 256, 0, stream>>>(f01, out_wb, out_g, out_b,
                                           (float*)d_out);
}

// Round 13
// 195.875 us; speedup vs baseline: 1.1507x; 1.1507x over previous
//
#include <hip/hip_runtime.h>
#include <hip/hip_bf16.h>

typedef unsigned short ushort_t;
typedef unsigned int uint_t;
typedef __attribute__((ext_vector_type(8))) short v8s;   // 8 x bf16 (4 VGPRs)
typedef __attribute__((ext_vector_type(4))) float v4f;   // MFMA accumulator / float4

#define BN_SCALE 0.9999950000374997f

__device__ __forceinline__ float bf2f(ushort_t u) {
    union { uint_t i; float f; } v;
    v.i = ((uint_t)u) << 16;
    return v.f;
}
__device__ __forceinline__ ushort_t f2bf(float f) {
    union { uint_t i; float f; } v;
    v.f = f;
    uint_t b = v.i;
    b += 0x7fffu + ((b >> 16) & 1u);   // RNE
    return (ushort_t)(b >> 16);
}

__device__ __forceinline__ v8s cvt8(const float* __restrict__ p) {
    v8s f;
    #pragma unroll
    for (int j = 0; j < 8; ++j) f[j] = (short)f2bf(p[j]);
    return f;
}

// ---------------------------------------------------------------------------
// Kernel 0: convert out_w + m0_w + m1_w (f32 -> bf16) in ONE launch.
// Blocks [0,64): out_w (65536 elem); [64,72): m0_w (8192); [72,80): m1_w.
// ---------------------------------------------------------------------------
__global__ __launch_bounds__(256) void convw_kernel(
    const float* __restrict__ out_w, ushort_t* __restrict__ out_wb,
    const float* __restrict__ m0_w,  ushort_t* __restrict__ m0_wb,
    const float* __restrict__ m1_w,  ushort_t* __restrict__ m1_wb)
{
    const float* src;
    ushort_t* dst;
    int base;
    const int b = blockIdx.x;
    if (b < 64)      { src = out_w; dst = out_wb; base = b; }
    else if (b < 72) { src = m0_w;  dst = m0_wb;  base = b - 64; }
    else             { src = m1_w;  dst = m1_wb;  base = b - 72; }
    const int i = (base * 256 + threadIdx.x) * 4;
    const v4f v = *(const v4f*)(src + i);
    ushort_t r0 = f2bf(v[0]), r1 = f2bf(v[1]), r2 = f2bf(v[2]), r3 = f2bf(v[3]);
    uint_t lo = (uint_t)r0 | ((uint_t)r1 << 16);
    uint_t hi = (uint_t)r2 | ((uint_t)r3 << 16);
    *(uint2*)(dst + i) = make_uint2(lo, hi);
}

// ---------------------------------------------------------------------------
// Kernel 1: cur{0,1}[n][d] = src_feats[n] . fc{0,1}_w[d] + fc{0,1}_b[d]
// Pure-MFMA GEMM, no LDS, bias folded into acc init. 64 rows/block.
// ---------------------------------------------------------------------------
__global__ __launch_bounds__(256) void cur_kernel(
    const float* __restrict__ src_feats,                     // (N,64) f32
    const float* __restrict__ fc0_w, const float* __restrict__ fc0_b,
    const float* __restrict__ fc1_w, const float* __restrict__ fc1_b,
    ushort_t* __restrict__ cur0, ushort_t* __restrict__ cur1)
{
    const int tid  = threadIdx.x;
    const int lane = tid & 63;
    const int wid  = tid >> 6;
    const int col  = lane & 15;
    const int quad = lane >> 4;
    const int row0 = blockIdx.x * 64 + wid * 16;

    v8s afrag[2];
    #pragma unroll
    for (int kf = 0; kf < 2; ++kf)
        afrag[kf] = cvt8(src_feats + (size_t)(row0 + col) * 64 + kf * 32 + quad * 8);

    v4f acc[8];
    v8s bfrag[8][2];
    #pragma unroll
    for (int ct = 0; ct < 8; ++ct) {
        const int d = (ct & 3) * 16 + col;
        const float* w = (ct < 4 ? fc0_w : fc1_w) + d * 64;
        const float  b = (ct < 4 ? fc0_b : fc1_b)[d];
        acc[ct] = (v4f){b, b, b, b};
        #pragma unroll
        for (int kf = 0; kf < 2; ++kf)
            bfrag[ct][kf] = cvt8(w + kf * 32 + quad * 8);
    }

    #pragma unroll
    for (int kf = 0; kf < 2; ++kf)
        #pragma unroll
        for (int ct = 0; ct < 8; ++ct)
            acc[ct] = __builtin_amdgcn_mfma_f32_16x16x32_bf16(
                afrag[kf], bfrag[ct][kf], acc[ct], 0, 0, 0);

    #pragma unroll
    for (int ct = 0; ct < 8; ++ct) {
        ushort_t* dst = (ct < 4) ? cur0 : cur1;
        const int d = (ct & 3) * 16 + col;
        #pragma unroll
        for (int r = 0; r < 4; ++r) {
            const int n = row0 + quad * 4 + r;
            dst[(size_t)n * 64 + d] = f2bf(acc[ct][r]);
        }
    }
}

// ---------------------------------------------------------------------------
// SA layer body (R10 structure). 128 pairs/block, 256 threads (4 waves).
// Prologue: cur rows -> xlds (coalesced b128); (sp-dp) -> flds.
// Phase A (paired-d): lane handles pair=lane>>5, d=(lane&31)*2 +{0,1}.
// Phase B: per-wave col-split (2 cts/wave) over MB independent m's; bfrag
//   hoisted per block from pre-converted bf16 m_wb (direct v8s loads).
// ---------------------------------------------------------------------------
template <int S>
__device__ __forceinline__ void sa_body(
    const int bid,
    const float* __restrict__ src_xyz,   // (N,3) f32
    const float* __restrict__ dst_xyz,   // (M,3) f32
    const int*   __restrict__ idx,       // (M,S)
    const int*   __restrict__ empty,     // (M,)
    const float* __restrict__ p_w,       // (64,6)
    const float* __restrict__ p_g,
    const float* __restrict__ p_b,
    const ushort_t* __restrict__ m_wb,   // (128,64) bf16 (pre-converted)
    const float* __restrict__ m_g,
    const float* __restrict__ m_b,
    const ushort_t* __restrict__ cur,    // (N,64) bf16
    ushort_t*    __restrict__ f01,       // (M,256) bf16
    const int layer_off,
    ushort_t* xlds,                      // [128 * 72]
    v4f*      flds)                      // [128]
{
    constexpr int PAIRS = 128;
    constexpr int MB = PAIRS / S;        // 4 (S=32) or 8 (S=16)
    constexpr int XP = 72;               // padded row stride (ushorts), 144 B
    constexpr int T  = S / 4;            // pairs per (wave, mi) in phase A

    const int tid  = threadIdx.x;
    const int lane = tid & 63;
    const int wid  = tid >> 6;           // 0..3
    const int m0   = bid * MB;

    // ---- prologue 1: cur rows -> xlds (coalesced, in-place with x) ----
    {
        const int p  = tid >> 1;         // pair 0..127
        const int hf = tid & 1;
        const int m  = m0 + p / S;
        const int i  = idx[(size_t)m * S + (p & (S - 1))];
        const uint_t* crow = (const uint_t*)(cur + (size_t)i * 64) + hf * 16;
        const uint4 c0 = *(const uint4*)(crow + 0);
        const uint4 c1 = *(const uint4*)(crow + 4);
        const uint4 c2 = *(const uint4*)(crow + 8);
        const uint4 c3 = *(const uint4*)(crow + 12);
        uint_t* drow = (uint_t*)(xlds + p * XP) + hf * 16;
        *(uint4*)(drow + 0)  = c0;
        *(uint4*)(drow + 4)  = c1;
        *(uint4*)(drow + 8)  = c2;
        *(uint4*)(drow + 12) = c3;
    }
    // ---- prologue 2: relative coords -> flds ----
    if (tid < PAIRS) {
        const int p = tid;
        const int m = m0 + p / S;
        const int i = idx[(size_t)m * S + (p & (S - 1))];
        const float dx = dst_xyz[m * 3 + 0];
        const float dy = dst_xyz[m * 3 + 1];
        const float dz = dst_xyz[m * 3 + 2];
        v4f r;
        r[0] = src_xyz[i * 3 + 0] - dx;
        r[1] = src_xyz[i * 3 + 1] - dy;
        r[2] = src_xyz[i * 3 + 2] - dz;
        r[3] = 0.0f;
        flds[p] = r;
    }

    // ---- per-lane paired-d constants (d = dd, dd+1) ----
    const int dd = (lane & 31) * 2;
    const int psub = lane >> 5;          // 0/1: which pair of the iter
    const float pgA = p_g[dd] * BN_SCALE;
    const float pgB = p_g[dd + 1] * BN_SCALE;
    const float pbA = p_b[dd];
    const float pbB = p_b[dd + 1];
    const float pwA0 = p_w[dd * 6 + 0] * pgA;
    const float pwA1 = p_w[dd * 6 + 1] * pgA;
    const float pwA2 = p_w[dd * 6 + 2] * pgA;
    const float pdA0 = p_w[dd * 6 + 3] * pgA;
    const float pdA1 = p_w[dd * 6 + 4] * pgA;
    const float pdA2 = p_w[dd * 6 + 5] * pgA;
    const float pwB0 = p_w[dd * 6 + 6] * pgB;
    const float pwB1 = p_w[dd * 6 + 7] * pgB;
    const float pwB2 = p_w[dd * 6 + 8] * pgB;
    const float pdB0 = p_w[dd * 6 + 9] * pgB;
    const float pdB1 = p_w[dd * 6 + 10] * pgB;
    const float pdB2 = p_w[dd * 6 + 11] * pgB;

    __syncthreads();

    // ================= phase A: paired-d, pure LDS + VALU =================
    const int tbase = wid * T;
    #pragma unroll
    for (int mi = 0; mi < MB; ++mi) {
        const int m = m0 + mi;                        // uniform
        const float dx = dst_xyz[m * 3 + 0];          // s_load
        const float dy = dst_xyz[m * 3 + 1];
        const float dz = dst_xyz[m * 3 + 2];
        const int   em = empty[m];
        const float vbA = fmaf(pdA0, dx, fmaf(pdA1, dy, fmaf(pdA2, dz, pbA)));
        const float vbB = fmaf(pdB0, dx, fmaf(pdB1, dy, fmaf(pdB2, dz, pbB)));

        #pragma unroll
        for (int it = 0; it < T / 2; ++it) {
            const int p = mi * S + tbase + it * 2 + psub;
            const v4f r = flds[p];                    // 2-addr broadcast b128
            const uint_t cu = *(const uint_t*)(xlds + p * XP + dd);   // b32
            const float c0 = __uint_as_float(cu << 16);
            const float c1 = __uint_as_float(cu & 0xffff0000u);

            const float v0 = fmaf(pwA0, r[0], fmaf(pwA1, r[1], fmaf(pwA2, r[2], vbA)));
            const float v1 = fmaf(pwB0, r[0], fmaf(pwB1, r[1], fmaf(pwB2, r[2], vbB)));
            const float rc0 = __builtin_amdgcn_rcpf(1.0f + __expf(-v0));
            const float rc1 = __builtin_amdgcn_rcpf(1.0f + __expf(-v1));
            float x0 = fmaf(v0, rc0, c0);
            float x1 = fmaf(v1, rc1, c1);
            x0 = em ? 0.0f : x0;
            x1 = em ? 0.0f : x1;

            float2 f2; f2.x = x0; f2.y = x1;
            union { __hip_bfloat162 h2; uint_t u; } pk;
            pk.h2 = __float22bfloat162_rn(f2);        // v_cvt_pk_bf16_f32
            *(uint_t*)(xlds + p * XP + dd) = pk.u;    // b32 write in place
        }
    }

    // ---- phase-B per-wave constants (direct bf16 loads, no cvt) ----
    const int col  = lane & 15;
    const int quad = lane >> 4;
    v8s bfrag[2][2];                     // [ct][kf]
    float mgv[2], mbv[2];
    #pragma unroll
    for (int c = 0; c < 2; ++c) {
        const int h = (wid * 2 + c) * 16 + col;
        #pragma unroll
        for (int kf = 0; kf < 2; ++kf)
            bfrag[c][kf] = *(const v8s*)(m_wb + h * 64 + kf * 32 + quad * 8);
        mgv[c] = m_g[h] * BN_SCALE;
        mbv[c] = m_b[h];
    }

    __syncthreads();

    // ================= phase B: MB independent m's per wave =================
    #pragma unroll
    for (int mi = 0; mi < MB; ++mi) {
        const int m = m0 + mi;
        v4f acc[S / 16][2];
        #pragma unroll
        for (int rt = 0; rt < S / 16; ++rt)
            #pragma unroll
            for (int c = 0; c < 2; ++c)
                acc[rt][c] = (v4f)0.0f;

        #pragma unroll
        for (int rt = 0; rt < S / 16; ++rt) {
            #pragma unroll
            for (int kf = 0; kf < 2; ++kf) {
                const v8s afrag = *(const v8s*)(
                    xlds + ((mi * S + rt * 16 + col)) * XP + kf * 32 + quad * 8);
                acc[rt][0] = __builtin_amdgcn_mfma_f32_16x16x32_bf16(
                    afrag, bfrag[0][kf], acc[rt][0], 0, 0, 0);
                acc[rt][1] = __builtin_amdgcn_mfma_f32_16x16x32_bf16(
                    afrag, bfrag[1][kf], acc[rt][1], 0, 0, 0);
            }
        }

        // epilogue: bn, relu, max over s (C/D layout: col=lane&15, row=quad*4+r)
        float vmax0 = 0.0f, vmax1 = 0.0f;
        #pragma unroll
        for (int c = 0; c < 2; ++c) {
            float vm = 0.0f;   // relu(y)>=0, so 0 is a valid identity
            #pragma unroll
            for (int rt = 0; rt < S / 16; ++rt)
                #pragma unroll
                for (int r = 0; r < 4; ++r) {
                    const float y = fmaf(acc[rt][c][r], mgv[c], mbv[c]);
                    vm = fmaxf(vm, y);
                }
            vm = fmaxf(vm, __shfl_xor(vm, 16));
            vm = fmaxf(vm, __shfl_xor(vm, 32));
            if (c == 0) vmax0 = vm; else vmax1 = vm;
        }
        if (lane < 32) {
            const int c = lane >> 4;
            const float val = (c == 0) ? vmax0 : vmax1;
            f01[m * 256 + layer_off + (wid * 2 + c) * 16 + (lane & 15)] = f2bf(val);
        }
    }
}

// ---------------------------------------------------------------------------
// Kernel 2: fused SA layers. Blocks [0, G32) run layer 1 (S=32), blocks
// [G32, G32+G16) run layer 0 (S=16).
// ---------------------------------------------------------------------------
__global__ __launch_bounds__(256, 6) void sa_fused_kernel(
    const float* __restrict__ src_xyz, const float* __restrict__ dst_xyz,
    const int* __restrict__ idx0, const int* __restrict__ empty0,
    const float* __restrict__ p0_w, const float* __restrict__ p0_g, const float* __restrict__ p0_b,
    const ushort_t* __restrict__ m0_wb, const float* __restrict__ m0_g, const float* __restrict__ m0_b,
    const ushort_t* __restrict__ cur0,
    const int* __restrict__ idx1, const int* __restrict__ empty1,
    const float* __restrict__ p1_w, const float* __restrict__ p1_g, const float* __restrict__ p1_b,
    const ushort_t* __restrict__ m1_wb, const float* __restrict__ m1_g, const float* __restrict__ m1_b,
    const ushort_t* __restrict__ cur1,
    ushort_t* __restrict__ f01, const int G32)
{
    __shared__ ushort_t xlds[128 * 72];  // 18432 B
    __shared__ v4f      flds[128];       //  2048 B

    const int b = blockIdx.x;
    if (b < G32)
        sa_body<32>(b, src_xyz, dst_xyz, idx1, empty1, p1_w, p1_g, p1_b,
                    m1_wb, m1_g, m1_b, cur1, f01, 128, xlds, flds);
    else
        sa_body<16>(b - G32, src_xyz, dst_xyz, idx0, empty0, p0_w, p0_g, p0_b,
                    m0_wb, m0_g, m0_b, cur0, f01, 0, xlds, flds);
}

// ---------------------------------------------------------------------------
// Kernel 4: out[m][o] = relu(bn(f01[m] . out_w[o])) via MFMA.
// 16 rows/block, 4 waves split the 256 output cols, K=256.
// ---------------------------------------------------------------------------
__global__ __launch_bounds__(256) void out_kernel(
    const ushort_t* __restrict__ f01,     // (M,256) bf16
    const ushort_t* __restrict__ out_wb,  // (256,256) bf16
    const float*    __restrict__ out_g,
    const float*    __restrict__ out_b,
    float*          __restrict__ out)     // (M,256) f32
{
    const int tid  = threadIdx.x;
    const int lane = tid & 63;
    const int wid  = tid >> 6;
    const int col  = lane & 15;
    const int quad = lane >> 4;
    const int m0   = blockIdx.x * 16;

    v8s afrag[8];
    #pragma unroll
    for (int kf = 0; kf < 8; ++kf)
        afrag[kf] = *(const v8s*)(f01 + (size_t)(m0 + col) * 256 + kf * 32 + quad * 8);

    v4f acc[4];
    #pragma unroll
    for (int c = 0; c < 4; ++c) acc[c] = (v4f)0.0f;

    #pragma unroll
    for (int kf = 0; kf < 8; ++kf) {
        #pragma unroll
        for (int c = 0; c < 4; ++c) {
            const int n = (wid * 4 + c) * 16 + col;
            const v8s b = *(const v8s*)(out_wb + (size_t)n * 256 + kf * 32 + quad * 8);
            acc[c] = __builtin_amdgcn_mfma_f32_16x16x32_bf16(afrag[kf], b, acc[c], 0, 0, 0);
        }
    }

    #pragma unroll
    for (int c = 0; c < 4; ++c) {
        const int n  = (wid * 4 + c) * 16 + col;
        const float og = out_g[n] * BN_SCALE;
        const float ob = out_b[n];
        #pragma unroll
        for (int r = 0; r < 4; ++r) {
            float y = fmaf(acc[c][r], og, ob);
            y = fmaxf(y, 0.0f);
            out[(size_t)(m0 + quad * 4 + r) * 256 + n] = y;
        }
    }
}

// ---------------------------------------------------------------------------
extern "C" void kernel_launch(void* const* d_in, const int* in_sizes, int n_in,
                              void* d_out, int out_size, void* d_ws, size_t ws_size,
                              hipStream_t stream)
{
    const float* src_xyz   = (const float*)d_in[0];
    const float* src_feats = (const float*)d_in[1];
    const float* dst_xyz   = (const float*)d_in[2];
    const int*   idx0      = (const int*)d_in[3];
    const int*   idx1      = (const int*)d_in[4];
    const int*   empty0    = (const int*)d_in[5];
    const int*   empty1    = (const int*)d_in[6];
    const float* fc0_w     = (const float*)d_in[7];
    const float* fc0_b     = (const float*)d_in[8];
    const float* p0_w      = (const float*)d_in[9];
    const float* p0_g      = (const float*)d_in[10];
    const float* p0_b      = (const float*)d_in[11];
    const float* m0_w      = (const float*)d_in[12];
    const float* m0_g      = (const float*)d_in[13];
    const float* m0_b      = (const float*)d_in[14];
    const float* fc1_w     = (const float*)d_in[15];
    const float* fc1_b     = (const float*)d_in[16];
    const float* p1_w      = (const float*)d_in[17];
    const float* p1_g      = (const float*)d_in[18];
    const float* p1_b      = (const float*)d_in[19];
    const float* m1_w      = (const float*)d_in[20];
    const float* m1_g      = (const float*)d_in[21];
    const float* m1_b      = (const float*)d_in[22];
    const float* out_w     = (const float*)d_in[23];
    const float* out_g     = (const float*)d_in[24];
    const float* out_b     = (const float*)d_in[25];

    const int N = in_sizes[0] / 3;   // 65536
    const int M = in_sizes[2] / 3;   // 16384

    // ws layout: cur0 | cur1 (N*64 bf16) | f01 (M*256 bf16) | out_wb | m0_wb | m1_wb
    ushort_t* cur0   = (ushort_t*)d_ws;
    ushort_t* cur1   = cur0 + (size_t)N * 64;
    ushort_t* f01    = cur1 + (size_t)N * 64;
    ushort_t* out_wb = f01 + (size_t)M * 256;
    ushort_t* m0_wb  = out_wb + 256 * 256;
    ushort_t* m1_wb  = m0_wb + 128 * 64;

    const int G32 = M / 4;   // sa32: MB=4
    const int G16 = M / 8;   // sa16: MB=8

    convw_kernel<<<80, 256, 0, stream>>>(out_w, out_wb, m0_w, m0_wb, m1_w, m1_wb);
    cur_kernel<<<N / 64, 256, 0, stream>>>(src_feats, fc0_w, fc0_b, fc1_w, fc1_b,
                                           cur0, cur1);
    sa_fused_kernel<<<G32 + G16, 256, 0, stream>>>(
        src_xyz, dst_xyz,
        idx0, empty0, p0_w, p0_g, p0_b, m0_wb, m0_g, m0_b, cur0,
        idx1, empty1, p1_w, p1_g, p1_b, m1_wb, m1_g, m1_b, cur1,
        f01, G32);
    out_kernel<<<M / 16, 256, 0, stream>>>(f01, out_wb, out_g, out_b,
                                           (float*)d_out);
}